// Round 1
// baseline (191.582 us; speedup 1.0000x reference)
//
#include <hip/hip_runtime.h>
#include <math.h>

// Problem constants (B,C,H,W) = (16,128,128,128); only tensor[0] (8 MB) is used.
#define HH 128
#define WW 128
#define NPAIRS (HH * WW)   // 16384 (j,k) pairs

// Kernel 1: argmax of tensor[0,0] (first 16384 floats), first-occurrence
// semantics (strict '>' while scanning increasing indices; min-index on tie
// in the reduction). Also zeroes d_out (poisoned 0xAA each launch) so
// kernel 2 can atomicAdd.
__global__ void argmax_init_kernel(const float* __restrict__ t,
                                   float* __restrict__ ws,
                                   float* __restrict__ out) {
    __shared__ float sval[256];
    __shared__ int   sidx[256];
    const int tid = threadIdx.x;

    float best = -INFINITY;
    int   bi   = 0;
    // Each thread scans indices in increasing order -> local first-occurrence.
    for (int i = tid; i < NPAIRS; i += 256) {
        float v = t[i];
        if (v > best) { best = v; bi = i; }
    }
    sval[tid] = best;
    sidx[tid] = bi;
    __syncthreads();

    for (int s = 128; s > 0; s >>= 1) {
        if (tid < s) {
            float ov = sval[tid + s];
            int   oi = sidx[tid + s];
            if (ov > sval[tid] || (ov == sval[tid] && oi < sidx[tid])) {
                sval[tid] = ov;
                sidx[tid] = oi;
            }
        }
        __syncthreads();
    }

    if (tid == 0) {
        int idx = sidx[0];
        ws[0] = (float)(idx / WW);  // x0
        ws[1] = (float)(idx % WW);  // y0
    }
    if (tid < WW) out[tid] = 0.0f;
}

// Kernel 2: out[w] += sum over rows p in this block's slice of
//   wgt(p) * t[p*128 + w],  wgt(p) = (x0 - (p>>7))^2 + (y0 - (p&127))^2.
// Grid: 256 blocks x (128,2) threads; each block covers 64 rows.
__global__ void wsum_kernel(const float* __restrict__ t,
                            const float* __restrict__ ws,
                            float* __restrict__ out) {
    const int w  = threadIdx.x;   // 0..127
    const int ty = threadIdx.y;   // 0..1
    const float x0 = ws[0];
    const float y0 = ws[1];

    const int rowBase = blockIdx.x * 64;
    float acc = 0.0f;
#pragma unroll 4
    for (int r = ty; r < 64; r += 2) {
        const int p = rowBase + r;
        const float j = (float)(p >> 7);
        const float k = (float)(p & 127);
        const float dj = x0 - j;
        const float dk = y0 - k;
        const float wgt = dj * dj + dk * dk;
        acc += wgt * t[p * WW + w];
    }

    __shared__ float smem[2][WW];
    smem[ty][w] = acc;
    __syncthreads();
    if (ty == 0) {
        atomicAdd(&out[w], smem[0][w] + smem[1][w]);
    }
}

extern "C" void kernel_launch(void* const* d_in, const int* in_sizes, int n_in,
                              void* d_out, int out_size, void* d_ws, size_t ws_size,
                              hipStream_t stream) {
    const float* t  = (const float*)d_in[0];
    float* out      = (float*)d_out;   // 128 fp32
    float* ws       = (float*)d_ws;    // ws[0]=x0, ws[1]=y0

    argmax_init_kernel<<<1, 256, 0, stream>>>(t, ws, out);
    wsum_kernel<<<256, dim3(128, 2), 0, stream>>>(t, ws, out);
}

// Round 2
// 165.829 us; speedup vs baseline: 1.1553x; 1.1553x over previous
//
#include <hip/hip_runtime.h>
#include <math.h>

// Problem constants (B,C,H,W) = (16,128,128,128); only tensor[0] (8 MB) is used.
#define HH 128
#define WW 128
#define NPAIRS (HH * WW)   // 16384 (j,k) pairs

// Kernel 1: argmax of tensor[0,0] (first 16384 floats), first-occurrence
// semantics. float4 loads: 256 threads x 16 float4 = 16384 elements.
// Each thread scans increasing indices with strict '>', so its local best is
// its first occurrence; the tree reduce breaks value-ties by min index.
// Also zeroes d_out (poisoned 0xAA each launch) so kernel 2 can atomicAdd.
__global__ __launch_bounds__(256) void argmax_init_kernel(
        const float* __restrict__ t,
        float* __restrict__ ws,
        float* __restrict__ out) {
    __shared__ float sval[256];
    __shared__ int   sidx[256];
    const int tid = threadIdx.x;

    const float4* t4 = reinterpret_cast<const float4*>(t);
    float best = -INFINITY;
    int   bi   = 0;
#pragma unroll
    for (int v = 0; v < 16; ++v) {
        const int vi = tid + v * 256;        // float4 index, increasing per thread
        const float4 x = t4[vi];
        const int base = vi * 4;
        if (x.x > best) { best = x.x; bi = base + 0; }
        if (x.y > best) { best = x.y; bi = base + 1; }
        if (x.z > best) { best = x.z; bi = base + 2; }
        if (x.w > best) { best = x.w; bi = base + 3; }
    }
    sval[tid] = best;
    sidx[tid] = bi;
    __syncthreads();

    for (int s = 128; s > 0; s >>= 1) {
        if (tid < s) {
            const float ov = sval[tid + s];
            const int   oi = sidx[tid + s];
            if (ov > sval[tid] || (ov == sval[tid] && oi < sidx[tid])) {
                sval[tid] = ov;
                sidx[tid] = oi;
            }
        }
        __syncthreads();
    }

    if (tid == 0) {
        const int idx = sidx[0];
        ws[0] = (float)(idx / WW);  // x0
        ws[1] = (float)(idx % WW);  // y0
    }
    if (tid < WW) out[tid] = 0.0f;
}

// Kernel 2: out[w] += sum over rows p of wgt(p) * t[p*128 + w],
//   wgt(p) = (x0 - (p>>7))^2 + (y0 - (p&127))^2.
// Grid: 256 blocks x 256 threads; each block covers 64 rows via float4 loads:
// thread (q = tid&31, rty = tid>>5) handles w in [4q,4q+4) for rows
// rowBase + rty + 8*it, it = 0..7. Wave of 64 lanes = 2 rows x 512 B, dwordx4.
__global__ __launch_bounds__(256) void wsum_kernel(
        const float* __restrict__ t,
        const float* __restrict__ ws,
        float* __restrict__ out) {
    const int tid = threadIdx.x;
    const int q   = tid & 31;   // w-quad: w0 = 4q
    const int rty = tid >> 5;   // 0..7
    const float x0 = ws[0];
    const float y0 = ws[1];

    const int rowBase = blockIdx.x * 64;
    const float4* t4 = reinterpret_cast<const float4*>(t);

    float4 acc = make_float4(0.f, 0.f, 0.f, 0.f);
#pragma unroll
    for (int it = 0; it < 8; ++it) {
        const int p = rowBase + rty + it * 8;
        const float dj = x0 - (float)(p >> 7);
        const float dk = y0 - (float)(p & 127);
        const float wgt = dj * dj + dk * dk;
        const float4 v = t4[p * (WW / 4) + q];
        acc.x += wgt * v.x;
        acc.y += wgt * v.y;
        acc.z += wgt * v.z;
        acc.w += wgt * v.w;
    }

    __shared__ float part[8][WW];   // [rty][w]
    part[rty][q * 4 + 0] = acc.x;
    part[rty][q * 4 + 1] = acc.y;
    part[rty][q * 4 + 2] = acc.z;
    part[rty][q * 4 + 3] = acc.w;
    __syncthreads();

    if (tid < WW) {
        float s = 0.f;
#pragma unroll
        for (int r = 0; r < 8; ++r) s += part[r][tid];
        atomicAdd(&out[tid], s);
    }
}

extern "C" void kernel_launch(void* const* d_in, const int* in_sizes, int n_in,
                              void* d_out, int out_size, void* d_ws, size_t ws_size,
                              hipStream_t stream) {
    const float* t  = (const float*)d_in[0];
    float* out      = (float*)d_out;   // 128 fp32
    float* ws       = (float*)d_ws;    // ws[0]=x0, ws[1]=y0

    argmax_init_kernel<<<1, 256, 0, stream>>>(t, ws, out);
    wsum_kernel<<<256, 256, 0, stream>>>(t, ws, out);
}